// Round 1
// baseline (157.634 us; speedup 1.0000x reference)
//
#include <hip/hip_runtime.h>
#include <math.h>

#define N_NODES 1024
#define IN_F 512
#define N_HEADS 4
#define N_HID 32
#define OUT_F 128   // N_HEADS*N_HID
#define NEG_SLOPE 0.2f

// ---------------- Kernel A: g_l = h@W_l, g_r = h@W_r ----------------
// 256 blocks: even blocks -> W_l, odd -> W_r; each block does 8 rows x 128 cols.
__global__ __launch_bounds__(256) void gat_gemm(
    const float* __restrict__ hmat, const float* __restrict__ Wl,
    const float* __restrict__ Wr, float* __restrict__ gl, float* __restrict__ gr)
{
  const int which = blockIdx.x & 1;
  const int r0 = (blockIdx.x >> 1) * 8;
  const float* __restrict__ W = which ? Wr : Wl;
  float* __restrict__ outp = which ? gr : gl;
  __shared__ float hs[8][IN_F];
  const float4* hsrc = (const float4*)(hmat + (size_t)r0 * IN_F);
  float4* hdst = (float4*)hs;
#pragma unroll
  for (int it = 0; it < 4; ++it)
    hdst[threadIdx.x + it * 256] = hsrc[threadIdx.x + it * 256];
  __syncthreads();
  const int r = threadIdx.x >> 5;   // 0..7
  const int c4 = threadIdx.x & 31;  // float4 column group
  float4 acc = make_float4(0.f, 0.f, 0.f, 0.f);
#pragma unroll 4
  for (int k = 0; k < IN_F; ++k) {
    float a = hs[r][k];
    float4 w = ((const float4*)(W + (size_t)k * OUT_F))[c4];
    acc.x = fmaf(a, w.x, acc.x);
    acc.y = fmaf(a, w.y, acc.y);
    acc.z = fmaf(a, w.z, acc.z);
    acc.w = fmaf(a, w.w, acc.w);
  }
  ((float4*)(outp + (size_t)(r0 + r) * OUT_F))[c4] = acc;
}

// ---------------- Kernel B: e[h][i][j] = sum_f lrelu(gl[j]+gr[i]) * aw[f] ----
// grid (32,32): bi = i-tile, bj = j-tile. 256 threads.
// thread = (jl = tid&31, h = (tid>>5)&3, i2 = tid>>7); loops 16 i's.
__global__ __launch_bounds__(256) void gat_escore(
    const float* __restrict__ gl, const float* __restrict__ gr,
    const float* __restrict__ attn_w, float* __restrict__ e)
{
  __shared__ float glt[32][132];  // pad 128->132 to break 512B-stride bank conflicts
  __shared__ float grt[32][132];
  const int bi = blockIdx.x, bj = blockIdx.y;
  {
    int f4 = threadIdx.x & 31;
    int row = threadIdx.x >> 5;  // 0..7
#pragma unroll
    for (int rr = 0; rr < 4; ++rr) {
      int rw = row + rr * 8;
      *(float4*)&glt[rw][f4 * 4] =
          ((const float4*)(gl + (size_t)(bj * 32 + rw) * OUT_F))[f4];
      *(float4*)&grt[rw][f4 * 4] =
          ((const float4*)(gr + (size_t)(bi * 32 + rw) * OUT_F))[f4];
    }
  }
  float aw[N_HID];
#pragma unroll
  for (int f = 0; f < N_HID; ++f) aw[f] = attn_w[f];  // uniform -> s_loads
  __syncthreads();

  const int jl = threadIdx.x & 31;
  const int hh = (threadIdx.x >> 5) & 3;
  const int i2 = threadIdx.x >> 7;  // 0..1

  float gg[N_HID];
#pragma unroll
  for (int f4 = 0; f4 < 8; ++f4) {
    float4 v = *(const float4*)&glt[jl][hh * N_HID + f4 * 4];
    gg[f4 * 4 + 0] = v.x; gg[f4 * 4 + 1] = v.y;
    gg[f4 * 4 + 2] = v.z; gg[f4 * 4 + 3] = v.w;
  }
  float* ebase = e + ((size_t)hh * N_NODES + (size_t)bi * 32) * N_NODES +
                 (size_t)bj * 32 + jl;
#pragma unroll 1
  for (int ii = 0; ii < 16; ++ii) {
    const int il = i2 * 16 + ii;
    float acc = 0.f;
#pragma unroll
    for (int f4 = 0; f4 < 8; ++f4) {
      float4 rv = *(const float4*)&grt[il][hh * N_HID + f4 * 4];
      float s;
      s = gg[f4 * 4 + 0] + rv.x;
      acc = fmaf(fmaxf(s, NEG_SLOPE * s), aw[f4 * 4 + 0], acc);
      s = gg[f4 * 4 + 1] + rv.y;
      acc = fmaf(fmaxf(s, NEG_SLOPE * s), aw[f4 * 4 + 1], acc);
      s = gg[f4 * 4 + 2] + rv.z;
      acc = fmaf(fmaxf(s, NEG_SLOPE * s), aw[f4 * 4 + 2], acc);
      s = gg[f4 * 4 + 3] + rv.w;
      acc = fmaf(fmaxf(s, NEG_SLOPE * s), aw[f4 * 4 + 3], acc);
    }
    ebase[(size_t)il * N_NODES] = acc;
  }
}

// ---------------- Kernel C: masked softmax over j, in place ----------------
// grid (1024, 4): blockIdx.x = i, blockIdx.y = h. 256 threads, 4 j's each.
__global__ __launch_bounds__(256) void gat_softmax(
    float* __restrict__ e, const int* __restrict__ adj)
{
  const int i = blockIdx.x, hh = blockIdx.y;
  float* row = e + ((size_t)hh * N_NODES + i) * N_NODES;
  const int t = threadIdx.x;
  float4 v = ((const float4*)row)[t];
  int4 ad = ((const int4*)(adj + (size_t)i * N_NODES))[t];
  v.x = ad.x ? v.x : -1e30f;
  v.y = ad.y ? v.y : -1e30f;
  v.z = ad.z ? v.z : -1e30f;
  v.w = ad.w ? v.w : -1e30f;
  float m = fmaxf(fmaxf(v.x, v.y), fmaxf(v.z, v.w));
#pragma unroll
  for (int d = 1; d < 64; d <<= 1) m = fmaxf(m, __shfl_xor(m, d));
  __shared__ float red[4];
  if ((t & 63) == 0) red[t >> 6] = m;
  __syncthreads();
  m = fmaxf(fmaxf(red[0], red[1]), fmaxf(red[2], red[3]));
  float p0 = __expf(v.x - m), p1 = __expf(v.y - m);
  float p2 = __expf(v.z - m), p3 = __expf(v.w - m);
  float s = p0 + p1 + p2 + p3;
#pragma unroll
  for (int d = 1; d < 64; d <<= 1) s += __shfl_xor(s, d);
  __shared__ float red2[4];
  if ((t & 63) == 0) red2[t >> 6] = s;
  __syncthreads();
  s = red2[0] + red2[1] + red2[2] + red2[3];
  float inv = 1.0f / s;
  ((float4*)row)[t] = make_float4(p0 * inv, p1 * inv, p2 * inv, p3 * inv);
}

// ---------------- Kernel D: h'[i, h*32+f] = sum_j a[h][i][j]*gr[j][h*32+f]; ELU
// 512 blocks: bh = bx>>7 (head), it = bx&127 (8 i's each). 256 threads.
__global__ __launch_bounds__(256) void gat_aggregate(
    const float* __restrict__ a, const float* __restrict__ gr,
    float* __restrict__ outp)
{
  const int bh = blockIdx.x >> 7;
  const int it = blockIdx.x & 127;
  const int f = threadIdx.x & 31;
  const int il = threadIdx.x >> 5;  // 0..7
  const int i = it * 8 + il;
  const float4* arow = (const float4*)(a + ((size_t)bh * N_NODES + i) * N_NODES);
  const float* gcol = gr + bh * N_HID + f;
  float acc = 0.f;
#pragma unroll 4
  for (int j4 = 0; j4 < N_NODES / 4; ++j4) {
    float4 av = arow[j4];
    acc = fmaf(av.x, gcol[(size_t)(j4 * 4 + 0) * OUT_F], acc);
    acc = fmaf(av.y, gcol[(size_t)(j4 * 4 + 1) * OUT_F], acc);
    acc = fmaf(av.z, gcol[(size_t)(j4 * 4 + 2) * OUT_F], acc);
    acc = fmaf(av.w, gcol[(size_t)(j4 * 4 + 3) * OUT_F], acc);
  }
  float r = acc > 0.f ? acc : expm1f(acc);
  outp[(size_t)i * OUT_F + bh * N_HID + f] = r;
}

extern "C" void kernel_launch(void* const* d_in, const int* in_sizes, int n_in,
                              void* d_out, int out_size, void* d_ws, size_t ws_size,
                              hipStream_t stream) {
  const float* hmat  = (const float*)d_in[0];
  const int*   adj   = (const int*)d_in[1];
  const float* Wl    = (const float*)d_in[2];
  const float* Wr    = (const float*)d_in[3];
  const float* attnw = (const float*)d_in[4];
  float* outp = (float*)d_out;

  char* ws = (char*)d_ws;
  float* gl = (float*)ws;                          // 1024*128 f32 = 512 KB
  float* gr = (float*)(ws + 512 * 1024);           // 512 KB
  float* e  = (float*)(ws + 1024 * 1024);          // 4*1024*1024 f32 = 16 MB

  gat_gemm<<<256, 256, 0, stream>>>(hmat, Wl, Wr, gl, gr);
  gat_escore<<<dim3(32, 32), 256, 0, stream>>>(gl, gr, attnw, e);
  gat_softmax<<<dim3(1024, 4), 256, 0, stream>>>(e, adj);
  gat_aggregate<<<512, 256, 0, stream>>>(e, gr, outp);
}